// Round 7
// baseline (719.806 us; speedup 1.0000x reference)
//
#include <hip/hip_runtime.h>
#include <stdint.h>

typedef unsigned int       u32;
typedef unsigned long long u64;
typedef unsigned short     u16;
typedef unsigned char      u8;

typedef float f32x4 __attribute__((ext_vector_type(4)));
typedef int   i32x4 __attribute__((ext_vector_type(4)));
typedef int   i32x8 __attribute__((ext_vector_type(8)));

#define AS1 __attribute__((address_space(1)))
#define AS3 __attribute__((address_space(3)))

constexpr int BATCH = 8, SEQ = 2048, DIM = 512, CODES = 8192;
constexpr int MROWS = BATCH * SEQ;          // 16384
constexpr int CAP   = 128;                  // candidate slots per row
#define MARGIN          20.0f               // fp8 d2 err sigma ~2.3; 20 ~ 6 sigma of pair-diff
#define RESCORE_MARGIN  20.0f

// ---- ordered-uint encode for float min ----
__device__ __forceinline__ u32 encf(float f) {
    u32 u = __float_as_uint(f);
    return (u & 0x80000000u) ? ~u : (u | 0x80000000u);
}
__device__ __forceinline__ float decf(u32 e) {
    return (e & 0x80000000u) ? __uint_as_float(e & 0x7fffffffu) : __uint_as_float(~e);
}

// ---- software fp32 -> fp8 e4m3fn (OCP), RTNE ----
__device__ __forceinline__ u32 f2fp8(float f) {
    u32 u = __float_as_uint(f);
    u32 s = (u >> 24) & 0x80u;
    float a = fabsf(f);
    if (a >= 448.f) return s | 0x7Eu;                 // clamp to max normal
    if (a < 0.015625f) {                              // subnormal: multiples of 2^-9
        u32 mi = (u32)rintf(a * 512.0f);              // 0..8 (8 carries to min normal)
        return s | mi;
    }
    u32 b = __float_as_uint(a);
    b += 0x7FFFFu + ((b >> 20) & 1u);                 // RTNE to 3 mantissa bits
    u32 e = b >> 23;                                  // 121..135
    return s | ((e - 120u) << 3) | ((b >> 20) & 7u);
}

// ---------------- pass 0: fused fp32->fp8 cast + numpy-pairwise-exact row sumsq ----------------
// Blocks 0..255 -> x, 256..383 -> codebook; also zeroes cnt and inits gmin.
__global__ __launch_bounds__(256) void k_prep(const float* __restrict__ x,
                                              const float* __restrict__ cb,
                                              u8* __restrict__ dx,
                                              u8* __restrict__ dcb,
                                              float* __restrict__ x2,
                                              float* __restrict__ c2,
                                              u32* __restrict__ cnt,
                                              u32* __restrict__ gmin) {
#pragma clang fp contract(off)
    __shared__ float lp[64 * 133];
    const int t  = threadIdx.x;
    const int bx = blockIdx.x;
    const int gid = bx * 256 + t;
    if (gid < MROWS) { cnt[gid] = 0u; gmin[gid] = 0xFFFFFFFFu; }

    const float* src; u8* dst; float* dsq; int row0;
    if (bx < 256) { src = x;  dst = dx;  dsq = x2; row0 = bx * 64; }
    else          { src = cb; dst = dcb; dsq = c2; row0 = (bx - 256) * 64; }

    float blk[4];
    for (int p = 0; p < 4; p++) {
#pragma unroll
        for (int k = 0; k < 8; k++) {
            int idx = t + 256 * k;
            int row = idx >> 5, c4 = idx & 31;
            const float* gp = src + (size_t)(row0 + row) * DIM + p * 128 + c4 * 4;
            float4 v = *(const float4*)gp;
            u32 pk = f2fp8(v.x) | (f2fp8(v.y) << 8) | (f2fp8(v.z) << 16) | (f2fp8(v.w) << 24);
            *(u32*)(dst + (size_t)(row0 + row) * DIM + p * 128 + c4 * 4) = pk;
            int la = row * 133 + c4 * 4;
            lp[la] = v.x; lp[la + 1] = v.y; lp[la + 2] = v.z; lp[la + 3] = v.w;
        }
        __syncthreads();
        if (t < 64) {
            const float* q = lp + t * 133;
            float a0 = q[0]*q[0], a1 = q[1]*q[1], a2 = q[2]*q[2], a3 = q[3]*q[3];
            float a4 = q[4]*q[4], a5 = q[5]*q[5], a6 = q[6]*q[6], a7 = q[7]*q[7];
            for (int i = 1; i < 16; i++) {
                const float* r = q + i * 8;
                a0 = a0 + r[0]*r[0]; a1 = a1 + r[1]*r[1];
                a2 = a2 + r[2]*r[2]; a3 = a3 + r[3]*r[3];
                a4 = a4 + r[4]*r[4]; a5 = a5 + r[5]*r[5];
                a6 = a6 + r[6]*r[6]; a7 = a7 + r[7]*r[7];
            }
            blk[p] = ((a0 + a1) + (a2 + a3)) + ((a4 + a5) + (a6 + a7));
        }
        __syncthreads();
    }
    if (t < 64) dsq[row0 + t] = (blk[0] + blk[1]) + (blk[2] + blk[3]);
}

// ---------------- pass 1: MX-fp8 16x16x128 MFMA GEMM, 128x128 tiles, 3 blocks/CU ----------------
// grid = 8192: bx>>6 = row-tile (128 rows), bx&63 = col-tile (128 cols); consecutive
// bx share a row-tile (XCD-L2 reuse of A). 256 thr / 4 waves; wave-tile 64x64 via
// 4x4 grid of 16x16x128 MFMAs (acc 64 VGPR). Single-buffered 2-barrier K-loop
// (4 iters of BK=128); XOR-16B-chunk swizzle (rows are 128 B, same as bf16 BK=64).
// Thresholds share a global per-row running min (device atomicMin) to bound appends.
__global__ __launch_bounds__(256, 3) void k_vq(const u8* __restrict__ A,   // [16384,512] fp8
                                               const u8* __restrict__ B,   // [8192,512] fp8
                                               const float* __restrict__ c2,
                                               u32* __restrict__ cnt,
                                               uint2* __restrict__ cand,
                                               u32* __restrict__ gmin) {
    __shared__ u32 lA32[4096];              // 16 KiB  A tile 128x128 fp8
    __shared__ u32 lB32[4096];              // 16 KiB  B tile 128x128 fp8
    __shared__ u32 mrow[128];

    const int t    = threadIdx.x;
    const int wave = t >> 6, lane = t & 63;
    const int lr   = lane & 15, quad = lane >> 4;
    const int bx   = blockIdx.x;
    const int row0 = (bx >> 6) * 128;
    const int col0 = (bx & 63) * 128;
    const int wRow = (wave >> 1) * 64;
    const int wCol = (wave & 1) * 64;

    if (t < 128) mrow[t] = 0xFFFFFFFFu;

    f32x4 acc[4][4];
#pragma unroll
    for (int i = 0; i < 4; i++)
#pragma unroll
        for (int j = 0; j < 4; j++) { f32x4 z = {0.f, 0.f, 0.f, 0.f}; acc[i][j] = z; }

    for (int it = 0; it < 4; it++) {
        __syncthreads();                    // prev iter's ds_reads done (WAR)
        const int kb = it * 128;
#pragma unroll
        for (int p = 0; p < 4; p++) {
            int off = t * 16 + p * 4096;    // byte offset in 16 KiB tile
            int rr  = off >> 7;             // tile row (128 B/row)
            int cc  = (off >> 4) & 7;       // LDS chunk position
            int sc  = ((cc ^ (rr & 7)) << 4);   // source byte col (XOR swizzle)
            const u8* ga = A + (size_t)(row0 + rr) * DIM + kb + sc;
            const u8* gb = B + (size_t)(col0 + rr) * DIM + kb + sc;
            __builtin_amdgcn_global_load_lds((const AS1 u32*)ga,
                                             (AS3 u32*)((char*)lA32 + off), 16, 0, 0);
            __builtin_amdgcn_global_load_lds((const AS1 u32*)gb,
                                             (AS3 u32*)((char*)lB32 + off), 16, 0, 0);
        }
        __syncthreads();                    // staging visible

        i32x8 af[4], bf[4];
#pragma unroll
        for (int mi = 0; mi < 4; mi++) {    // A frag: lane holds A[m=lane&15][k=quad*32 + 0..31]
            int r = wRow + mi * 16 + lr;
            const char* base = (const char*)lA32 + r * 128;
            int c0 = quad * 2;
            i32x4 lo = *(const i32x4*)(base + (((c0    ) ^ (r & 7)) << 4));
            i32x4 hi = *(const i32x4*)(base + (((c0 + 1) ^ (r & 7)) << 4));
            af[mi] = __builtin_shufflevector(lo, hi, 0, 1, 2, 3, 4, 5, 6, 7);
        }
#pragma unroll
        for (int ni = 0; ni < 4; ni++) {
            int r = wCol + ni * 16 + lr;
            const char* base = (const char*)lB32 + r * 128;
            int c0 = quad * 2;
            i32x4 lo = *(const i32x4*)(base + (((c0    ) ^ (r & 7)) << 4));
            i32x4 hi = *(const i32x4*)(base + (((c0 + 1) ^ (r & 7)) << 4));
            bf[ni] = __builtin_shufflevector(lo, hi, 0, 1, 2, 3, 4, 5, 6, 7);
        }
#pragma unroll
        for (int mi = 0; mi < 4; mi++)
#pragma unroll
            for (int ni = 0; ni < 4; ni++)
                acc[mi][ni] = __builtin_amdgcn_mfma_scale_f32_16x16x128_f8f6f4(
                    af[mi], bf[ni], acc[mi][ni],
                    0, 0,                        // cbsz = fp8 e4m3 (A), blgp = fp8 e4m3 (B)
                    0, 0x7F7F7F7Fu,              // scale A: e8m0 = 127 -> 2^0
                    0, 0x7F7F7F7Fu);             // scale B: unit
    }

    // ---- epilogue: C-layout row = quad*4+reg, col = lane&15 ----
    float c2v[4];
#pragma unroll
    for (int ni = 0; ni < 4; ni++) c2v[ni] = c2[col0 + wCol + ni * 16 + lr];

#pragma unroll
    for (int mi = 0; mi < 4; mi++) {
#pragma unroll
        for (int r4 = 0; r4 < 4; r4++) {
            float v0 = c2v[0] - 2.0f * acc[mi][0][r4];
            float v1 = c2v[1] - 2.0f * acc[mi][1][r4];
            float v2 = c2v[2] - 2.0f * acc[mi][2][r4];
            float v3 = c2v[3] - 2.0f * acc[mi][3][r4];
            float mn = fminf(fminf(v0, v1), fminf(v2, v3));
#pragma unroll
            for (int mask = 1; mask < 16; mask <<= 1)
                mn = fminf(mn, __shfl_xor(mn, mask));
            if (lr == 0) atomicMin(&mrow[wRow + mi * 16 + quad * 4 + r4], encf(mn));
        }
    }
    __syncthreads();
    if (t < 128) {                          // merge with global running min (device scope)
        u32 k = mrow[t];
        u32 old = atomicMin(&gmin[row0 + t], k);
        mrow[t] = old < k ? old : k;
    }
    __syncthreads();
#pragma unroll
    for (int mi = 0; mi < 4; mi++) {
#pragma unroll
        for (int r4 = 0; r4 < 4; r4++) {
            const int lrow = wRow + mi * 16 + quad * 4 + r4;
            const float th = decf(mrow[lrow]) + MARGIN;
            const int grow = row0 + lrow;
#pragma unroll
            for (int ni = 0; ni < 4; ni++) {
                float s = c2v[ni] - 2.0f * acc[mi][ni][r4];
                if (s < th) {
                    u32 idx = atomicAdd(&cnt[grow], 1u);
                    if (idx < CAP)
                        cand[(size_t)grow * CAP + idx] =
                            make_uint2(__float_as_uint(s), (u32)(col0 + wCol + ni * 16 + lr));
                }
            }
        }
    }
}

// ---------------- pass 2: exact rescore (fp64 dot, np-fp32 pipeline) + gather + PE ----------------
__global__ __launch_bounds__(256) void k_fin(const float* __restrict__ x,
                                             const float* __restrict__ cb,
                                             const float* __restrict__ c2,
                                             const float* __restrict__ x2,
                                             const u32* __restrict__ cnt,
                                             const uint2* __restrict__ cand,
                                             float* __restrict__ out) {
    const int row  = (blockIdx.x * 256 + threadIdx.x) >> 6;   // one wave per row
    const int lane = threadIdx.x & 63;
    int n = (int)cnt[row];
    if (n > CAP) n = CAP;
    if (n < 0) n = 0;
    const uint2* cd = cand + (size_t)row * CAP;

    float m = 3.4028235e38f;
    for (int i = lane; i < n; i += 64) m = fminf(m, __uint_as_float(cd[i].x));
#pragma unroll
    for (int mask = 32; mask; mask >>= 1) m = fminf(m, __shfl_xor(m, mask));
    const float thr = m + RESCORE_MARGIN;

    const float* xr = x + (size_t)row * DIM + lane * 8;
    float4 xv0 = *(const float4*)xr;
    float4 xv1 = *(const float4*)(xr + 4);
    const float x2v = x2[row];

    u64 best = ~0ull;
    for (int i = 0; i < n; i++) {
        uint2 e = cd[i];
        float sa = __uint_as_float(e.x);
        u32 ci = (e.y < (u32)CODES) ? e.y : 0u;                // harden gather index
        if (sa <= thr) {                                       // wave-uniform branch
            const float* cr = cb + (size_t)ci * DIM + lane * 8;
            float4 c0 = *(const float4*)cr;
            float4 c1 = *(const float4*)(cr + 4);
            double d = (double)xv0.x * c0.x + (double)xv0.y * c0.y +
                       (double)xv0.z * c0.z + (double)xv0.w * c0.w +
                       (double)xv1.x * c1.x + (double)xv1.y * c1.y +
                       (double)xv1.z * c1.z + (double)xv1.w * c1.w;
#pragma unroll
            for (int mask = 32; mask; mask >>= 1) d += __shfl_xor(d, mask);
            float dot = (float)d;
            float s32 = (x2v - 2.0f * dot) + c2[ci];           // np fp32 pipeline
            u64 key = ((u64)encf(s32) << 32) | (u64)ci;        // lowest-index tie-break
            best = best < key ? best : key;
        }
    }
    u32 wcol = (u32)(best & 0xffffffffu);
    if (wcol >= (u32)CODES) wcol = 0;                          // unreachable safety

    const float* cw = cb + (size_t)wcol * DIM + lane * 8;
    float4 q0 = *(const float4*)cw;
    float4 q1 = *(const float4*)(cw + 4);
    const int spos = row & (SEQ - 1);
    float pe[8];
#pragma unroll
    for (int ii = 0; ii < 4; ii++) {
        int ipair = lane * 4 + ii;
        float dt  = expf((float)(2 * ipair) * (-0.017988946039035083f)); // ln(1e4)/512
        float ang = (float)spos * dt;
        float sv, cv;
        sincosf(ang, &sv, &cv);
        pe[2 * ii]     = sv;
        pe[2 * ii + 1] = cv;
    }
    float4* op = (float4*)(out + (size_t)row * DIM + lane * 8);
    op[0] = make_float4(q0.x + pe[0], q0.y + pe[1], q0.z + pe[2], q0.w + pe[3]);
    op[1] = make_float4(q1.x + pe[4], q1.y + pe[5], q1.z + pe[6], q1.w + pe[7]);
}

extern "C" void kernel_launch(void* const* d_in, const int* in_sizes, int n_in,
                              void* d_out, int out_size, void* d_ws, size_t ws_size,
                              hipStream_t stream) {
    const float* x  = (const float*)d_in[0];   // [8,2048,512]
    const float* cb = (const float*)d_in[1];   // [8192,512]
    float* out = (float*)d_out;

    char* ws = (char*)d_ws;
    u8*    A8   = (u8*)ws;                                    // 8 MiB
    u8*    B8   = (u8*)(ws + 8388608);                        // 4 MiB
    float* c2   = (float*)(ws + 8388608 + 4194304);           // 32 KiB
    float* x2   = (float*)(ws + 8388608 + 4194304 + 32768);   // 64 KiB
    u32*   cnt  = (u32*)(ws + 8388608 + 4194304 + 32768 + 65536);             // 64 KiB
    u32*   gmin = (u32*)(ws + 8388608 + 4194304 + 32768 + 65536 + 65536);     // 64 KiB
    uint2* cand = (uint2*)(ws + 8388608 + 4194304 + 32768 + 65536 + 131072);  // 16 MiB

    k_prep<<<dim3(384), dim3(256), 0, stream>>>(x, cb, A8, B8, x2, c2, cnt, gmin);
    k_vq<<<dim3(8192), dim3(256), 0, stream>>>(A8, B8, c2, cnt, cand, gmin);
    k_fin<<<dim3(4096), dim3(256), 0, stream>>>(x, cb, c2, x2, cnt, cand, out);
}